// Round 1
// 2751.430 us; speedup vs baseline: 1.0989x; 1.0989x over previous
//
#include <hip/hip_runtime.h>

// LongBlock on MI355X (gfx950). Input dtype (f32 vs bf16) is AUTO-DETECTED at
// runtime (device-side flag). All intermediates are canonical bf16 (weights
// transposed+converted once per call). Output dtype follows the input flag.
// Pipeline: ln1 -> conv+silu -> {q,k,v,ig,og} GEMMs (bf16 MFMA, B^T staged) ->
// per-head norms -> chunked gated scan -> fused attn epilogue -> Wo GEMM(+x) ->
// ln2 -> MLP (gate GEMM, val GEMM w/ fused silu*mul, out GEMM w/ resid).
// GEMM: 256x256 tile, BK=64, 8 waves, 8-phase schedule w/ counted vmcnt(4),
// st_16x32 LDS swizzle via pre-swizzled global source (linear gload_lds dest),
// raw s_barrier (no vmcnt drain), setprio around MFMA clusters.  (m201 template)
// Workspace: liveness-packed arena, peak 256 MiB (8 slots x 32 MiB).

#define D_MODEL 2048
#define NHEADS 16
#define HEADDIM 128
#define FFDIM 8192
#define BSZ 2
#define TLEN 4096
#define MTOK (BSZ * TLEN)
#define CHUNK 128
#define NCHUNK (TLEN / CHUNK)

typedef unsigned short u16;
typedef __attribute__((ext_vector_type(8))) short bf16x8;
typedef __attribute__((ext_vector_type(4))) float f32x4;

__device__ __forceinline__ float bf2f(unsigned u) {
    u <<= 16;
    float f;
    __builtin_memcpy(&f, &u, 4);
    return f;
}
__device__ __forceinline__ u16 f2bf(float f) {
    unsigned u;
    __builtin_memcpy(&u, &f, 4);
    u = u + 0x7fffu + ((u >> 16) & 1u);   // RNE
    return (u16)(u >> 16);
}
__device__ __forceinline__ void unpack8(uint4 p, float* v) {
    v[0] = bf2f(p.x & 0xffffu); v[1] = bf2f(p.x >> 16);
    v[2] = bf2f(p.y & 0xffffu); v[3] = bf2f(p.y >> 16);
    v[4] = bf2f(p.z & 0xffffu); v[5] = bf2f(p.z >> 16);
    v[6] = bf2f(p.w & 0xffffu); v[7] = bf2f(p.w >> 16);
}
__device__ __forceinline__ uint4 pack8(const float* v) {
    uint4 p;
    p.x = (unsigned)f2bf(v[0]) | ((unsigned)f2bf(v[1]) << 16);
    p.y = (unsigned)f2bf(v[2]) | ((unsigned)f2bf(v[3]) << 16);
    p.z = (unsigned)f2bf(v[4]) | ((unsigned)f2bf(v[5]) << 16);
    p.w = (unsigned)f2bf(v[6]) | ((unsigned)f2bf(v[7]) << 16);
    return p;
}
__device__ __forceinline__ float sigmoidf_(float x) { return 1.0f / (1.0f + __expf(-x)); }

// dtype-flag helpers: f != 0 => buffer is float32, else bf16
__device__ __forceinline__ float ld1f(const void* p, size_t i, int f) {
    return f ? ((const float*)p)[i] : bf2f(((const u16*)p)[i]);
}
__device__ __forceinline__ void ld8f(const void* p, size_t i, int f, float* v) {
    if (f) {
        const float4* fp = (const float4*)((const float*)p + i);
        float4 a = fp[0], b = fp[1];
        v[0] = a.x; v[1] = a.y; v[2] = a.z; v[3] = a.w;
        v[4] = b.x; v[5] = b.y; v[6] = b.z; v[7] = b.w;
    } else {
        uint4 q = *(const uint4*)((const u16*)p + i);
        unpack8(q, v);
    }
}

__device__ __forceinline__ void async16(const u16* g, u16* l) {
    __builtin_amdgcn_global_load_lds((const __attribute__((address_space(1))) void*)g,
                                     (__attribute__((address_space(3))) void*)l, 16, 0, 0);
}

// ---------------- dtype detector: count exponent==0xFF u16 patterns in x ----------------
__global__ __launch_bounds__(256) void detect_k(const u16* __restrict__ probe, int* __restrict__ flag) {
    int tid = threadIdx.x;
    int cnt = 0;
    for (int i = tid; i < 16384; i += 256) {
        unsigned e = (probe[i] >> 7) & 0xFFu;
        if (e == 0xFFu) cnt++;
    }
#pragma unroll
    for (int off = 32; off; off >>= 1) cnt += __shfl_xor(cnt, off, 64);
    __shared__ int tot[4];
    if ((tid & 63) == 0) tot[tid >> 6] = cnt;
    __syncthreads();
    if (tid == 0) flag[0] = (tot[0] + tot[1] + tot[2] + tot[3] > 4) ? 1 : 0;
}

__global__ void copyflag_k(const int* __restrict__ a, int* __restrict__ b) { b[0] = a[0]; }

// ---------------- weight transpose+convert: in[K,N] (flagged) -> out[N,K] bf16 ----------------
__global__ __launch_bounds__(256) void transpose_k(const void* __restrict__ in, u16* __restrict__ out,
                                                   int K, int N, const int* __restrict__ fl) {
    int f = *fl;
    __shared__ u16 tile[32][33];
    int n0 = blockIdx.x * 32, k0 = blockIdx.y * 32;
    int tx = threadIdx.x, ty = threadIdx.y;  // (32,8)
#pragma unroll
    for (int j = 0; j < 4; ++j)
        tile[ty + j * 8][tx] = f2bf(ld1f(in, (size_t)(k0 + ty + j * 8) * N + n0 + tx, f));
    __syncthreads();
#pragma unroll
    for (int j = 0; j < 4; ++j)
        out[(size_t)(n0 + ty + j * 8) * K + k0 + tx] = tile[tx][ty + j * 8];
}

// ---------------- LayerNorm over C=2048; block per row ----------------
template <int IN_RAW>
__global__ __launch_bounds__(256) void ln_rows(const void* __restrict__ in, u16* __restrict__ out,
                                               const void* __restrict__ w, const void* __restrict__ bb,
                                               const int* __restrict__ fl) {
    int f = *fl;
    int m = blockIdx.x, tid = threadIdx.x;
    size_t base = (size_t)m * D_MODEL + tid * 8;
    float v[8];
    ld8f(in, base, IN_RAW ? f : 0, v);
    float s = 0.f, ss = 0.f;
#pragma unroll
    for (int i = 0; i < 8; ++i) { s += v[i]; ss += v[i] * v[i]; }
#pragma unroll
    for (int off = 32; off; off >>= 1) { s += __shfl_xor(s, off, 64); ss += __shfl_xor(ss, off, 64); }
    __shared__ float red[8];
    int lane = tid & 63, wvi = tid >> 6;
    if (lane == 0) { red[wvi] = s; red[4 + wvi] = ss; }
    __syncthreads();
    s = red[0] + red[1] + red[2] + red[3];
    ss = red[4] + red[5] + red[6] + red[7];
    float mu = s * (1.f / D_MODEL);
    float var = ss * (1.f / D_MODEL) - mu * mu;
    float rs = rsqrtf(var + 1e-5f);
    int ci = tid * 8;
    float o[8];
#pragma unroll
    for (int i = 0; i < 8; ++i)
        o[i] = (v[i] - mu) * rs * ld1f(w, ci + i, f) + ld1f(bb, ci + i, f);
    *(uint4*)&out[base] = pack8(o);
}

// ---------------- depthwise causal conv K=4 + silu ----------------
__global__ __launch_bounds__(256) void conv_silu_k(const u16* __restrict__ h, const void* __restrict__ cw,
                                                   const void* __restrict__ cb, u16* __restrict__ out,
                                                   const int* __restrict__ fl) {
    int f = *fl;
    int m = blockIdx.x, tid = threadIdx.x;
    int b = m >> 12, t = m & (TLEN - 1);
    int c = tid * 8;
    float acc[8];
#pragma unroll
    for (int i = 0; i < 8; ++i) acc[i] = ld1f(cb, c + i, f);
    float wv[8][4];
#pragma unroll
    for (int i = 0; i < 8; ++i) {
        if (f) {
            float4 wp = *(const float4*)((const float*)cw + (size_t)(c + i) * 4);
            wv[i][0] = wp.x; wv[i][1] = wp.y; wv[i][2] = wp.z; wv[i][3] = wp.w;
        } else {
            uint2 wp = *(const uint2*)((const u16*)cw + (size_t)(c + i) * 4);
            wv[i][0] = bf2f(wp.x & 0xffffu); wv[i][1] = bf2f(wp.x >> 16);
            wv[i][2] = bf2f(wp.y & 0xffffu); wv[i][3] = bf2f(wp.y >> 16);
        }
    }
#pragma unroll
    for (int j = 0; j < 4; ++j) {
        int tj = t - 3 + j;
        if (tj < 0) continue;
        uint4 hp = *(const uint4*)&h[((size_t)(b * TLEN + tj)) * D_MODEL + c];
        float hv[8];
        unpack8(hp, hv);
#pragma unroll
        for (int i = 0; i < 8; ++i) acc[i] += wv[i][j] * hv[i];
    }
    float o[8];
#pragma unroll
    for (int i = 0; i < 8; ++i) o[i] = acc[i] * sigmoidf_(acc[i]);
    *(uint4*)&out[(size_t)m * D_MODEL + c] = pack8(o);
}

// ---------------- bf16 GEMM: C[m,n] = sum_k A[m,k]*BT[n,k] ----------------
// 256x256 tile, BK=64, 512 thr (8 waves, 2Mx4N), 128 KiB LDS double-buffer,
// 8-phase schedule: per phase {ds_read subtile; stage 1 half-tile (2x
// global_load_lds); s_barrier; setprio(1); 16 MFMA; setprio(0); s_barrier}.
// Counted s_waitcnt vmcnt(4) at phases 4/8 only (loads stay in flight across
// barriers). st_16x32 swizzle: LDS stays LINEAR (gload_lds constraint); the
// GLOBAL source col is pre-swizzled, reads apply the same XOR (involution).
// Tail: stage addrs clamp to tile NT-1 with FIXED buffer targets so the
// vmcnt counting stays uniform (predicating stages would break it).
// EPI 0: bf16 store.
// EPI 1: bf16 = sigmoid(acc + rawbias[n])            (aux raw-flagged)
// EPI 2: bf16 = acc + raw_resid[m,n]                 (aux raw-flagged, e.g. x)
// EPI 3: bf16 = silu(bf16 aux[m,n]) * acc            (aux canonical; may alias out)
// EPI 4: out[oofs+m*N+n] = acc + bf16 aux[m,n]; out dtype per flag (f32/bf16)
template <int EPI>
__global__ __launch_bounds__(512, 2) void gemm256(const u16* __restrict__ A, const u16* __restrict__ BT,
                                                  void* out, const void* aux, const int* fl,
                                                  long long oofs, int M, int N, int K) {
    __shared__ u16 As[2][16384];   // [buf][256 rows][64 k]
    __shared__ u16 Bs[2][16384];
    const int tid = threadIdx.x;
    const int lane = tid & 63;
    const int wv = tid >> 6;       // wave 0..7
    const int wm = wv >> 2;        // 0..1  (M half: 128 rows)
    const int wn = wv & 3;         // 0..3  (N quarter: 64 cols)
    const int m0 = blockIdx.y * 256, n0 = blockIdx.x * 256;

    // staging: thread stages rows r0 (q=0) / r0+64 (q=1) of each 128-row half,
    // cols (tid&7)*8; st_16x32 swizzle on the GLOBAL source col (dest linear).
    const int r0 = tid >> 3;
    const int cS = ((tid & 7) << 3) ^ ((r0 & 4) << 2);
    const u16* aB = A + (size_t)(m0 + r0) * K + cS;
    const u16* bB = BT + (size_t)(n0 + r0) * K + cS;

    // read-side fragment offsets (ushort units), same XOR on col
    const int fr = lane & 15;
    const int kq = (lane >> 4) << 3;
    const int sw = (fr & 4) << 2;
    const int rdA0 = (wm * 128 + fr) * 64 + (kq ^ sw);
    const int rdA1 = (wm * 128 + fr) * 64 + ((32 + kq) ^ sw);
    const int rdB0 = (wn * 64 + fr) * 64 + (kq ^ sw);
    const int rdB1 = (wn * 64 + fr) * 64 + ((32 + kq) ^ sw);

    f32x4 acc[8][4];
#pragma unroll
    for (int i = 0; i < 8; ++i)
#pragma unroll
        for (int j = 0; j < 4; ++j) acc[i][j] = (f32x4)0.0f;

    bf16x8 a[4][2], b0[2][2], b1[2][2];

#define BARX() asm volatile("s_barrier" ::: "memory")
#define WAITV(n) asm volatile("s_waitcnt vmcnt(" #n ")" ::: "memory")
#define STG_A(sel, h, tI)                                                                        \
    do {                                                                                         \
        async16(aB + (size_t)((h) * 128) * K + (size_t)(tI) * 64,                                \
                &As[sel][(h) * 8192 + (tid >> 6) * 512]);                                        \
        async16(aB + (size_t)((h) * 128 + 64) * K + (size_t)(tI) * 64,                           \
                &As[sel][(h) * 8192 + 4096 + (tid >> 6) * 512]);                                 \
    } while (0)
#define STG_B(sel, h, tI)                                                                        \
    do {                                                                                         \
        async16(bB + (size_t)((h) * 128) * K + (size_t)(tI) * 64,                                \
                &Bs[sel][(h) * 8192 + (tid >> 6) * 512]);                                        \
        async16(bB + (size_t)((h) * 128 + 64) * K + (size_t)(tI) * 64,                           \
                &Bs[sel][(h) * 8192 + 4096 + (tid >> 6) * 512]);                                 \
    } while (0)
#define LDA4(s, base)                                                                            \
    do {                                                                                         \
        a[0][0] = *(const bf16x8*)&As[s][rdA0 + (base + 0) * 1024];                              \
        a[0][1] = *(const bf16x8*)&As[s][rdA1 + (base + 0) * 1024];                              \
        a[1][0] = *(const bf16x8*)&As[s][rdA0 + (base + 1) * 1024];                              \
        a[1][1] = *(const bf16x8*)&As[s][rdA1 + (base + 1) * 1024];                              \
        a[2][0] = *(const bf16x8*)&As[s][rdA0 + (base + 2) * 1024];                              \
        a[2][1] = *(const bf16x8*)&As[s][rdA1 + (base + 2) * 1024];                              \
        a[3][0] = *(const bf16x8*)&As[s][rdA0 + (base + 3) * 1024];                              \
        a[3][1] = *(const bf16x8*)&As[s][rdA1 + (base + 3) * 1024];                              \
    } while (0)
#define LDB2(s, base, bb)                                                                        \
    do {                                                                                         \
        bb[0][0] = *(const bf16x8*)&Bs[s][rdB0 + (base + 0) * 1024];                             \
        bb[0][1] = *(const bf16x8*)&Bs[s][rdB1 + (base + 0) * 1024];                             \
        bb[1][0] = *(const bf16x8*)&Bs[s][rdB0 + (base + 1) * 1024];                             \
        bb[1][1] = *(const bf16x8*)&Bs[s][rdB1 + (base + 1) * 1024];                             \
    } while (0)
#define MM8(I0, J0, bb)                                                                          \
    do {                                                                                         \
        __builtin_amdgcn_s_setprio(1);                                                           \
        _Pragma("unroll") for (int i_ = 0; i_ < 4; ++i_) {                                       \
            _Pragma("unroll") for (int j_ = 0; j_ < 2; ++j_) {                                   \
                acc[(I0) + i_][(J0) + j_] = __builtin_amdgcn_mfma_f32_16x16x32_bf16(             \
                    a[i_][0], bb[j_][0], acc[(I0) + i_][(J0) + j_], 0, 0, 0);                    \
                acc[(I0) + i_][(J0) + j_] = __builtin_amdgcn_mfma_f32_16x16x32_bf16(             \
                    a[i_][1], bb[j_][1], acc[(I0) + i_][(J0) + j_], 0, 0, 0);                    \
            }                                                                                    \
        }                                                                                        \
        __builtin_amdgcn_s_setprio(0);                                                           \
    } while (0)

    // prologue: tile0 full + B halves of tile1; force tile0 landed (4 newest ok)
    STG_A(0, 0, 0);
    STG_A(0, 1, 0);
    STG_B(0, 0, 0);
    STG_B(0, 1, 0);
    STG_B(1, 0, 1);
    STG_B(1, 1, 1);
    WAITV(4);
    BARX();

    const int NT = K >> 6;
    for (int t = 0; t < NT; t += 2) {
        const int tn = t + 1;
        const int t2 = (t + 2 < NT) ? t + 2 : NT - 1;
        const int t3 = (t + 3 < NT) ? t + 3 : NT - 1;
        // phase 1: tile t Q(M0-3,N0-1); stage A-h0(t+1)->buf1
        LDA4(0, 0);
        LDB2(0, 0, b0);
        STG_A(1, 0, tn);
        BARX();
        MM8(0, 0, b0);
        BARX();
        // phase 2: Q(M0-3,N2-3); stage A-h1(t+1)->buf1
        LDB2(0, 2, b1);
        STG_A(1, 1, tn);
        BARX();
        MM8(0, 2, b1);
        BARX();
        // phase 3: Q(M4-7,N0-1); stage B-h0(t+2)->buf0 (buf0.B reads done ph2)
        LDA4(0, 4);
        STG_B(0, 0, t2);
        BARX();
        MM8(4, 0, b0);
        BARX();
        // phase 4: Q(M4-7,N2-3); stage B-h1(t+2)->buf0; force tile t+1 landed
        STG_B(0, 1, t2);
        BARX();
        MM8(4, 2, b1);
        WAITV(4);
        BARX();
        // phase 5: tile t+1 Q(M0-3,N0-1); stage A-h0(t+2)->buf0 (buf0.A reads done ph3)
        LDA4(1, 0);
        LDB2(1, 0, b0);
        STG_A(0, 0, t2);
        BARX();
        MM8(0, 0, b0);
        BARX();
        // phase 6: Q(M0-3,N2-3); stage A-h1(t+2)->buf0
        LDB2(1, 2, b1);
        STG_A(0, 1, t2);
        BARX();
        MM8(0, 2, b1);
        BARX();
        // phase 7: Q(M4-7,N0-1); stage B-h0(t+3)->buf1 (buf1.B reads done ph6)
        LDA4(1, 4);
        STG_B(1, 0, t3);
        BARX();
        MM8(4, 0, b0);
        BARX();
        // phase 8: Q(M4-7,N2-3); stage B-h1(t+3)->buf1; force tile t+2 landed
        STG_B(1, 1, t3);
        BARX();
        MM8(4, 2, b1);
        WAITV(4);
        BARX();
    }
    WAITV(0);  // drain clamped tail stages before endpgm

#undef BARX
#undef WAITV
#undef STG_A
#undef STG_B
#undef LDA4
#undef LDB2
#undef MM8

    int f = (EPI == 1 || EPI == 2 || EPI == 4) ? *fl : 0;
    const int col0 = n0 + wn * 64 + (lane & 15);
    const int row0 = m0 + wm * 128 + ((lane >> 4) << 2);
#pragma unroll
    for (int i = 0; i < 8; ++i) {
#pragma unroll
        for (int r = 0; r < 4; ++r) {
            int row = row0 + i * 16 + r;
            size_t base = (size_t)row * N;
#pragma unroll
            for (int j = 0; j < 4; ++j) {
                int col = col0 + j * 16;
                float v = acc[i][j][r];
                if (EPI == 0) {
                    ((u16*)out)[base + col] = f2bf(v);
                } else if (EPI == 1) {
                    ((u16*)out)[base + col] = f2bf(sigmoidf_(v + ld1f(aux, col, f)));
                } else if (EPI == 2) {
                    ((u16*)out)[base + col] = f2bf(v + ld1f(aux, base + col, f));
                } else if (EPI == 3) {
                    float g = bf2f(((const u16*)aux)[base + col]);
                    ((u16*)out)[base + col] = f2bf(g * sigmoidf_(g) * v);
                } else {
                    float hr = bf2f(((const u16*)aux)[base + col]);
                    if (f) ((float*)out)[oofs + base + col] = v + hr;
                    else   ((u16*)out)[oofs + base + col] = f2bf(v + hr);
                }
            }
        }
    }
}

// ---------------- per-head l2norm (in place) ----------------
__global__ __launch_bounds__(256) void l2norm_k(u16* __restrict__ x) {
    int m = blockIdx.x, tid = threadIdx.x;
    size_t base = (size_t)m * D_MODEL + tid * 8;
    uint4 p = *(const uint4*)&x[base];
    float v[8];
    unpack8(p, v);
    float s = 0.f;
#pragma unroll
    for (int i = 0; i < 8; ++i) s += v[i] * v[i];
    s += __shfl_xor(s, 1, 64); s += __shfl_xor(s, 2, 64);
    s += __shfl_xor(s, 4, 64); s += __shfl_xor(s, 8, 64);
    float sc = rsqrtf(s + 1e-12f);
    float o[8];
#pragma unroll
    for (int i = 0; i < 8; ++i) o[i] = v[i] * sc;
    *(uint4*)&x[base] = pack8(o);
}

// ---------------- per-head LayerNorm (in place), D=128 ----------------
__global__ __launch_bounds__(256) void vnorm_k(u16* __restrict__ x, const void* __restrict__ w,
                                               const void* __restrict__ bb, const int* __restrict__ fl) {
    int f = *fl;
    int m = blockIdx.x, tid = threadIdx.x;
    size_t base = (size_t)m * D_MODEL + tid * 8;
    uint4 p = *(const uint4*)&x[base];
    float v[8];
    unpack8(p, v);
    float s = 0.f, ss = 0.f;
#pragma unroll
    for (int i = 0; i < 8; ++i) { s += v[i]; ss += v[i] * v[i]; }
    s += __shfl_xor(s, 1, 64); s += __shfl_xor(s, 2, 64);
    s += __shfl_xor(s, 4, 64); s += __shfl_xor(s, 8, 64);
    ss += __shfl_xor(ss, 1, 64); ss += __shfl_xor(ss, 2, 64);
    ss += __shfl_xor(ss, 4, 64); ss += __shfl_xor(ss, 8, 64);
    float mu = s * (1.f / HEADDIM);
    float var = ss * (1.f / HEADDIM) - mu * mu;
    float rs = rsqrtf(var + 1e-5f);
    int d0 = (tid * 8) & 127;
    float o[8];
#pragma unroll
    for (int i = 0; i < 8; ++i) o[i] = (v[i] - mu) * rs * ld1f(w, d0 + i, f) + ld1f(bb, d0 + i, f);
    *(uint4*)&x[base] = pack8(o);
}

// ---------------- gamma[m,h] = sigmoid(xc[m,:] @ Wg[:,h] + bg[h]) ----------------
__global__ __launch_bounds__(256) void gamma_k(const u16* __restrict__ xc, const void* __restrict__ Wg,
                                               const void* __restrict__ bg, float* __restrict__ gamma,
                                               const int* __restrict__ fl) {
    int f = *fl;
    int m = blockIdx.x, tid = threadIdx.x;
    float g[16];
#pragma unroll
    for (int h = 0; h < 16; ++h) g[h] = 0.f;
    size_t base = (size_t)m * D_MODEL + tid * 8;
    uint4 xp = *(const uint4*)&xc[base];
    float xv[8];
    unpack8(xp, xv);
#pragma unroll
    for (int i = 0; i < 8; ++i) {
        float wv[16];
        size_t ro = (size_t)(tid * 8 + i) * 16;
        if (f) {
            const float4* wr = (const float4*)((const float*)Wg + ro);
#pragma unroll
            for (int q = 0; q < 4; ++q) {
                float4 w4 = wr[q];
                wv[q * 4 + 0] = w4.x; wv[q * 4 + 1] = w4.y; wv[q * 4 + 2] = w4.z; wv[q * 4 + 3] = w4.w;
            }
        } else {
            const u16* wrow = (const u16*)Wg + ro;
            uint4 w0 = *(const uint4*)&wrow[0];
            uint4 w1 = *(const uint4*)&wrow[8];
            unpack8(w0, wv);
            unpack8(w1, wv + 8);
        }
#pragma unroll
        for (int h = 0; h < 16; ++h) g[h] += xv[i] * wv[h];
    }
#pragma unroll
    for (int h = 0; h < 16; ++h)
#pragma unroll
        for (int off = 32; off; off >>= 1) g[h] += __shfl_xor(g[h], off, 64);
    __shared__ float part[4][16];
    int lane = tid & 63, wvi = tid >> 6;
    if (lane == 0)
#pragma unroll
        for (int h = 0; h < 16; ++h) part[wvi][h] = g[h];
    __syncthreads();
    if (tid < 16) {
        float s = part[0][tid] + part[1][tid] + part[2][tid] + part[3][tid] + ld1f(bg, tid, f);
        gamma[(size_t)m * 16 + tid] = sigmoidf_(s);
    }
}

// ---------------- chunked gated scan, phase 1: local scans + prefix products ----------------
__global__ __launch_bounds__(256) void scan1(const u16* __restrict__ ig, const u16* __restrict__ kn,
                                             const u16* __restrict__ vn, const float* __restrict__ gamma,
                                             float* __restrict__ mem, float* __restrict__ pp) {
    int idx = blockIdx.x;              // B * NCHUNK * 8
    int cblk = idx & 7, ch = (idx >> 3) & (NCHUNK - 1), b = idx >> 8;
    int c = cblk * 256 + threadIdx.x;
    int h = c >> 7;
    float mval = 0.f, p = 1.f;
    int t0 = ch * CHUNK;
    size_t rowbase = ((size_t)(b * TLEN + t0)) * D_MODEL + c;
    size_t grow = (size_t)(b * TLEN + t0) * 16 + h;
    bool writepp = ((c & 127) == 0);
    for (int s = 0; s < CHUNK; ++s) {
        float u = bf2f(ig[rowbase]) * bf2f(kn[rowbase]) * bf2f(vn[rowbase]);
        float g = gamma[grow];
        mval = g * mval + u;
        p *= g;
        mem[rowbase] = mval;
        if (writepp) pp[grow] = p;
        rowbase += D_MODEL;
        grow += 16;
    }
}

// ---------------- phase 2: serial carry across chunks ----------------
__global__ __launch_bounds__(256) void scan2(const float* __restrict__ mem, const float* __restrict__ pp,
                                             float* __restrict__ carry) {
    int idx = blockIdx.x * 256 + threadIdx.x;  // B*C = 4096
    int b = idx >> 11, c = idx & 2047, h = c >> 7;
    float cy = 0.f;
    for (int ch = 0; ch < NCHUNK; ++ch) {
        carry[((size_t)(b * NCHUNK + ch)) * D_MODEL + c] = cy;
        int tend = ch * CHUNK + CHUNK - 1;
        float P = pp[((size_t)(b * TLEN + tend)) * 16 + h];
        float le = mem[((size_t)(b * TLEN + tend)) * D_MODEL + c];
        cy = P * cy + le;
    }
}

// ---------------- attn epilogue: carry-fix + LN(mem)*q -> GroupNorm -> *og ----------------
__global__ __launch_bounds__(256) void attn_epi(const float* __restrict__ mem, const float* __restrict__ pp,
                                                const float* __restrict__ carry, const u16* __restrict__ qn,
                                                const u16* __restrict__ og, const void* __restrict__ mnw,
                                                const void* __restrict__ mnb, const void* __restrict__ gnw,
                                                const void* __restrict__ gnb, u16* __restrict__ outb,
                                                const int* __restrict__ fl) {
    int f = *fl;
    int m = blockIdx.x, tid = threadIdx.x;
    int b = m >> 12, t = m & (TLEN - 1);
    int ch = t >> 7;
    int c = tid * 8, h = c >> 7;
    size_t base = (size_t)m * D_MODEL + c;
    float mv[8];
    {
        const float4* p = (const float4*)&mem[base];
        float4 a = p[0], bb4 = p[1];
        mv[0] = a.x; mv[1] = a.y; mv[2] = a.z; mv[3] = a.w;
        mv[4] = bb4.x; mv[5] = bb4.y; mv[6] = bb4.z; mv[7] = bb4.w;
    }
    float ppv = pp[(size_t)m * 16 + h];
    {
        const float4* p = (const float4*)&carry[((size_t)(b * NCHUNK + ch)) * D_MODEL + c];
        float4 a = p[0], bb4 = p[1];
        mv[0] += ppv * a.x; mv[1] += ppv * a.y; mv[2] += ppv * a.z; mv[3] += ppv * a.w;
        mv[4] += ppv * bb4.x; mv[5] += ppv * bb4.y; mv[6] += ppv * bb4.z; mv[7] += ppv * bb4.w;
    }
    float s = 0.f, ss = 0.f;
#pragma unroll
    for (int i = 0; i < 8; ++i) { s += mv[i]; ss += mv[i] * mv[i]; }
    s += __shfl_xor(s, 1, 64); s += __shfl_xor(s, 2, 64);
    s += __shfl_xor(s, 4, 64); s += __shfl_xor(s, 8, 64);
    ss += __shfl_xor(ss, 1, 64); ss += __shfl_xor(ss, 2, 64);
    ss += __shfl_xor(ss, 4, 64); ss += __shfl_xor(ss, 8, 64);
    float mu = s * (1.f / HEADDIM);
    float var = ss * (1.f / HEADDIM) - mu * mu;
    float rs = rsqrtf(var + 1e-5f);
    int d0 = c & 127;
    uint4 qp = *(const uint4*)&qn[base];
    float qv[8];
    unpack8(qp, qv);
    float o[8];
#pragma unroll
    for (int i = 0; i < 8; ++i)
        o[i] = ((mv[i] - mu) * rs * ld1f(mnw, d0 + i, f) + ld1f(mnb, d0 + i, f)) * qv[i];
    float s2 = 0.f, ss2 = 0.f;
#pragma unroll
    for (int i = 0; i < 8; ++i) { s2 += o[i]; ss2 += o[i] * o[i]; }
    s2 += __shfl_xor(s2, 1, 64); s2 += __shfl_xor(s2, 2, 64);
    s2 += __shfl_xor(s2, 4, 64); s2 += __shfl_xor(s2, 8, 64);
    ss2 += __shfl_xor(ss2, 1, 64); ss2 += __shfl_xor(ss2, 2, 64);
    ss2 += __shfl_xor(ss2, 4, 64); ss2 += __shfl_xor(ss2, 8, 64);
    float mu2 = s2 * (1.f / HEADDIM);
    float var2 = ss2 * (1.f / HEADDIM) - mu2 * mu2;
    float rs2 = rsqrtf(var2 + 1e-5f);
    uint4 ogp = *(const uint4*)&og[base];
    float ogv[8];
    unpack8(ogp, ogv);
    float ob[8];
#pragma unroll
    for (int i = 0; i < 8; ++i)
        ob[i] = ((o[i] - mu2) * rs2 * ld1f(gnw, c + i, f) + ld1f(gnb, c + i, f)) * ogv[i];
    *(uint4*)&outb[base] = pack8(ob);
}

// ---------------- workspace arena: 8 slots x 32 MiB = 256 MiB peak ----------------
// slot0: wT (8 MiB, reused) + gamma/pp/carry/flagA @16MiB -> wTgate (32 MiB, MLP)
// slot1: hb      -> mem[lo]  -> wTval
// slot2: xcb     -> mem[hi]  -> wTout
// slot3: qn      -> h2b
// slot4: kn      -> attn     -> flagB (MLP phase)
// slot5: vn      -> hres (bf16)
// slot6: ig      -> graw[lo]
// slot7: og      -> graw[hi]
#define SLOT 33554432ull
#define WS_NEED (SLOT * 8)
#define FLAGA_OFF 18350080ull   /* slot0 + 16MiB + 1.5MiB (after carry) */
#define FLAGB_OFF (SLOT * 4)

extern "C" void kernel_launch(void* const* d_in, const int* in_sizes, int n_in,
                              void* d_out, int out_size, void* d_ws, size_t ws_size,
                              hipStream_t stream) {
    if (ws_size < WS_NEED) return;  // diagnostic guard: fail absmax instead of crashing

    const void* x     = d_in[0];
    const void* Wq    = d_in[1];
    const void* Wk    = d_in[2];
    const void* Wv    = d_in[3];
    const void* Wo    = d_in[4];
    const void* convw = d_in[5];
    const void* convb = d_in[6];
    const void* Wig   = d_in[7];
    const void* big   = d_in[8];
    const void* Wog   = d_in[9];
    const void* bog   = d_in[10];
    const void* Wg    = d_in[11];
    const void* bg    = d_in[12];
    const void* vnw   = d_in[13];
    const void* vnb   = d_in[14];
    const void* mnw   = d_in[15];
    const void* mnb   = d_in[16];
    const void* gnw   = d_in[17];
    const void* gnb   = d_in[18];
    const void* ln1w  = d_in[19];
    const void* ln1b  = d_in[20];
    const void* ln2w  = d_in[21];
    const void* ln2b  = d_in[22];
    const void* Wgate = d_in[23];
    const void* Wval  = d_in[24];
    const void* Wout  = d_in[25];

    char* ws = (char*)d_ws;
    u16* wT      = (u16*)(ws);
    float* gamma = (float*)(ws + 16777216);
    float* pp    = (float*)(ws + 16777216 + 524288);
    float* carry = (float*)(ws + 16777216 + 1048576);
    int* flagA   = (int*)(ws + FLAGA_OFF);
    int* flagB   = (int*)(ws + FLAGB_OFF);
    u16* hb      = (u16*)(ws + SLOT * 1);
    u16* xcb     = (u16*)(ws + SLOT * 2);
    float* mem   = (float*)(ws + SLOT * 1);          // spans slots 1-2 (f32)
    u16* wTgate  = (u16*)(ws);                       // slot0 (32 MiB), MLP phase
    u16* wTval   = (u16*)(ws + SLOT * 1);
    u16* wTout   = (u16*)(ws + SLOT * 2);
    u16* qn      = (u16*)(ws + SLOT * 3);
    u16* h2b     = (u16*)(ws + SLOT * 3);
    u16* kn      = (u16*)(ws + SLOT * 4);
    u16* attn    = (u16*)(ws + SLOT * 4);
    u16* vn      = (u16*)(ws + SLOT * 5);
    u16* hres    = (u16*)(ws + SLOT * 5);
    u16* ig      = (u16*)(ws + SLOT * 6);
    u16* og      = (u16*)(ws + SLOT * 7);
    u16* graw    = (u16*)(ws + SLOT * 6);            // spans slots 6-7

    dim3 tb(32, 8);

    detect_k<<<1, 256, 0, stream>>>((const u16*)x, flagA);

    // ---- attention front-end ----
    ln_rows<1><<<MTOK, 256, 0, stream>>>(x, hb, ln1w, ln1b, flagA);
    conv_silu_k<<<MTOK, 256, 0, stream>>>(hb, convw, convb, xcb, flagA);

    transpose_k<<<dim3(64, 64), tb, 0, stream>>>(Wq, wT, 2048, 2048, flagA);
    gemm256<0><<<dim3(8, 32), 512, 0, stream>>>(hb, wT, qn, nullptr, nullptr, 0, MTOK, 2048, 2048);
    transpose_k<<<dim3(64, 64), tb, 0, stream>>>(Wk, wT, 2048, 2048, flagA);
    gemm256<0><<<dim3(8, 32), 512, 0, stream>>>(hb, wT, kn, nullptr, nullptr, 0, MTOK, 2048, 2048);
    transpose_k<<<dim3(64, 64), tb, 0, stream>>>(Wv, wT, 2048, 2048, flagA);
    gemm256<0><<<dim3(8, 32), 512, 0, stream>>>(hb, wT, vn, nullptr, nullptr, 0, MTOK, 2048, 2048);
    l2norm_k<<<MTOK, 256, 0, stream>>>(qn);
    l2norm_k<<<MTOK, 256, 0, stream>>>(kn);
    vnorm_k<<<MTOK, 256, 0, stream>>>(vn, vnw, vnb, flagA);

    transpose_k<<<dim3(64, 64), tb, 0, stream>>>(Wig, wT, 2048, 2048, flagA);
    gemm256<1><<<dim3(8, 32), 512, 0, stream>>>(xcb, wT, ig, big, flagA, 0, MTOK, 2048, 2048);
    transpose_k<<<dim3(64, 64), tb, 0, stream>>>(Wog, wT, 2048, 2048, flagA);
    gemm256<1><<<dim3(8, 32), 512, 0, stream>>>(xcb, wT, og, bog, flagA, 0, MTOK, 2048, 2048);
    gamma_k<<<MTOK, 256, 0, stream>>>(xcb, Wg, bg, gamma, flagA);

    // ---- gated scan (mem overwrites hb/xcb slots — both dead) ----
    scan1<<<BSZ * NCHUNK * 8, 256, 0, stream>>>(ig, kn, vn, gamma, mem, pp);
    scan2<<<16, 256, 0, stream>>>(mem, pp, carry);
    attn_epi<<<MTOK, 256, 0, stream>>>(mem, pp, carry, qn, og, mnw, mnb, gnw, gnb, attn, flagA);

    // ---- output projection + residual (hres bf16) ----
    transpose_k<<<dim3(64, 64), tb, 0, stream>>>(Wo, wT, 2048, 2048, flagA);
    gemm256<2><<<dim3(8, 32), 512, 0, stream>>>(attn, wT, hres, x, flagA, 0, MTOK, 2048, 2048);
    ln_rows<0><<<MTOK, 256, 0, stream>>>(hres, h2b, ln2w, ln2b, flagA);

    // ---- flag to MLP-phase home (slot4 free after Wo gemm) ----
    copyflag_k<<<1, 1, 0, stream>>>(flagA, flagB);

    // ---- MLP: transpose all three weights once, then two M=4096 halves ----
    transpose_k<<<dim3(256, 64), tb, 0, stream>>>(Wgate, wTgate, 2048, 8192, flagB);
    transpose_k<<<dim3(256, 64), tb, 0, stream>>>(Wval, wTval, 2048, 8192, flagB);
    transpose_k<<<dim3(64, 256), tb, 0, stream>>>(Wout, wTout, 8192, 2048, flagB);

    for (int half = 0; half < 2; ++half) {
        const u16* a2 = h2b + (size_t)half * 4096 * 2048;
        const u16* hr = hres + (size_t)half * 4096 * 2048;
        long long oofs = (long long)half * 4096 * 2048;
        gemm256<0><<<dim3(32, 16), 512, 0, stream>>>(a2, wTgate, graw, nullptr, nullptr, 0, 4096, 8192, 2048);
        gemm256<3><<<dim3(32, 16), 512, 0, stream>>>(a2, wTval, graw, graw, nullptr, 0, 4096, 8192, 2048);
        gemm256<4><<<dim3(8, 16), 512, 0, stream>>>(graw, wTout, d_out, hr, flagB, oofs, 4096, 2048, 8192);
    }
}

// Round 2
// 2609.266 us; speedup vs baseline: 1.1588x; 1.0545x over previous
//
#include <hip/hip_runtime.h>

// LongBlock on MI355X (gfx950). Input dtype (f32 vs bf16) is AUTO-DETECTED at
// runtime (device-side flag). All intermediates are canonical bf16 (weights
// transposed+converted once per call). Output dtype follows the input flag.
// Pipeline: ln1 -> conv+silu -> {q,k,v,ig,og} GEMMs (bf16 MFMA, B^T staged) ->
// per-head norms -> chunked gated scan -> fused attn epilogue -> Wo GEMM(+x) ->
// ln2 -> MLP (gate GEMM, val GEMM w/ fused silu*mul, out GEMM w/ resid).
// GEMM: 256x256 tile, BK=64, 8 waves, 8-phase schedule w/ counted vmcnt(4),
// FULL-ROW XOR LDS swizzle (slot ^= row&7, 16B granularity) applied via
// pre-swizzled global source (linear gload_lds dest) + same XOR on ds_read —
// conflict-free b128 fragment reads (each aligned 8-lane group covers all 32
// banks). Raw s_barrier (no vmcnt drain), setprio around MFMA clusters.
// Workspace: liveness-packed arena, peak 256 MiB (8 slots x 32 MiB).

#define D_MODEL 2048
#define NHEADS 16
#define HEADDIM 128
#define FFDIM 8192
#define BSZ 2
#define TLEN 4096
#define MTOK (BSZ * TLEN)
#define CHUNK 128
#define NCHUNK (TLEN / CHUNK)

typedef unsigned short u16;
typedef __attribute__((ext_vector_type(8))) short bf16x8;
typedef __attribute__((ext_vector_type(4))) float f32x4;

__device__ __forceinline__ float bf2f(unsigned u) {
    u <<= 16;
    float f;
    __builtin_memcpy(&f, &u, 4);
    return f;
}
__device__ __forceinline__ u16 f2bf(float f) {
    unsigned u;
    __builtin_memcpy(&u, &f, 4);
    u = u + 0x7fffu + ((u >> 16) & 1u);   // RNE
    return (u16)(u >> 16);
}
__device__ __forceinline__ void unpack8(uint4 p, float* v) {
    v[0] = bf2f(p.x & 0xffffu); v[1] = bf2f(p.x >> 16);
    v[2] = bf2f(p.y & 0xffffu); v[3] = bf2f(p.y >> 16);
    v[4] = bf2f(p.z & 0xffffu); v[5] = bf2f(p.z >> 16);
    v[6] = bf2f(p.w & 0xffffu); v[7] = bf2f(p.w >> 16);
}
__device__ __forceinline__ uint4 pack8(const float* v) {
    uint4 p;
    p.x = (unsigned)f2bf(v[0]) | ((unsigned)f2bf(v[1]) << 16);
    p.y = (unsigned)f2bf(v[2]) | ((unsigned)f2bf(v[3]) << 16);
    p.z = (unsigned)f2bf(v[4]) | ((unsigned)f2bf(v[5]) << 16);
    p.w = (unsigned)f2bf(v[6]) | ((unsigned)f2bf(v[7]) << 16);
    return p;
}
__device__ __forceinline__ float sigmoidf_(float x) { return 1.0f / (1.0f + __expf(-x)); }

// dtype-flag helpers: f != 0 => buffer is float32, else bf16
__device__ __forceinline__ float ld1f(const void* p, size_t i, int f) {
    return f ? ((const float*)p)[i] : bf2f(((const u16*)p)[i]);
}
__device__ __forceinline__ void ld8f(const void* p, size_t i, int f, float* v) {
    if (f) {
        const float4* fp = (const float4*)((const float*)p + i);
        float4 a = fp[0], b = fp[1];
        v[0] = a.x; v[1] = a.y; v[2] = a.z; v[3] = a.w;
        v[4] = b.x; v[5] = b.y; v[6] = b.z; v[7] = b.w;
    } else {
        uint4 q = *(const uint4*)((const u16*)p + i);
        unpack8(q, v);
    }
}

__device__ __forceinline__ void async16(const u16* g, u16* l) {
    __builtin_amdgcn_global_load_lds((const __attribute__((address_space(1))) void*)g,
                                     (__attribute__((address_space(3))) void*)l, 16, 0, 0);
}

// ---------------- dtype detector: count exponent==0xFF u16 patterns in x ----------------
__global__ __launch_bounds__(256) void detect_k(const u16* __restrict__ probe, int* __restrict__ flag) {
    int tid = threadIdx.x;
    int cnt = 0;
    for (int i = tid; i < 16384; i += 256) {
        unsigned e = (probe[i] >> 7) & 0xFFu;
        if (e == 0xFFu) cnt++;
    }
#pragma unroll
    for (int off = 32; off; off >>= 1) cnt += __shfl_xor(cnt, off, 64);
    __shared__ int tot[4];
    if ((tid & 63) == 0) tot[tid >> 6] = cnt;
    __syncthreads();
    if (tid == 0) flag[0] = (tot[0] + tot[1] + tot[2] + tot[3] > 4) ? 1 : 0;
}

__global__ void copyflag_k(const int* __restrict__ a, int* __restrict__ b) { b[0] = a[0]; }

// ---------------- weight transpose+convert: in[K,N] (flagged) -> out[N,K] bf16 ----------------
__global__ __launch_bounds__(256) void transpose_k(const void* __restrict__ in, u16* __restrict__ out,
                                                   int K, int N, const int* __restrict__ fl) {
    int f = *fl;
    __shared__ u16 tile[32][33];
    int n0 = blockIdx.x * 32, k0 = blockIdx.y * 32;
    int tx = threadIdx.x, ty = threadIdx.y;  // (32,8)
#pragma unroll
    for (int j = 0; j < 4; ++j)
        tile[ty + j * 8][tx] = f2bf(ld1f(in, (size_t)(k0 + ty + j * 8) * N + n0 + tx, f));
    __syncthreads();
#pragma unroll
    for (int j = 0; j < 4; ++j)
        out[(size_t)(n0 + ty + j * 8) * K + k0 + tx] = tile[tx][ty + j * 8];
}

// ---------------- LayerNorm over C=2048; block per row ----------------
template <int IN_RAW>
__global__ __launch_bounds__(256) void ln_rows(const void* __restrict__ in, u16* __restrict__ out,
                                               const void* __restrict__ w, const void* __restrict__ bb,
                                               const int* __restrict__ fl) {
    int f = *fl;
    int m = blockIdx.x, tid = threadIdx.x;
    size_t base = (size_t)m * D_MODEL + tid * 8;
    float v[8];
    ld8f(in, base, IN_RAW ? f : 0, v);
    float s = 0.f, ss = 0.f;
#pragma unroll
    for (int i = 0; i < 8; ++i) { s += v[i]; ss += v[i] * v[i]; }
#pragma unroll
    for (int off = 32; off; off >>= 1) { s += __shfl_xor(s, off, 64); ss += __shfl_xor(ss, off, 64); }
    __shared__ float red[8];
    int lane = tid & 63, wvi = tid >> 6;
    if (lane == 0) { red[wvi] = s; red[4 + wvi] = ss; }
    __syncthreads();
    s = red[0] + red[1] + red[2] + red[3];
    ss = red[4] + red[5] + red[6] + red[7];
    float mu = s * (1.f / D_MODEL);
    float var = ss * (1.f / D_MODEL) - mu * mu;
    float rs = rsqrtf(var + 1e-5f);
    int ci = tid * 8;
    float o[8];
#pragma unroll
    for (int i = 0; i < 8; ++i)
        o[i] = (v[i] - mu) * rs * ld1f(w, ci + i, f) + ld1f(bb, ci + i, f);
    *(uint4*)&out[base] = pack8(o);
}

// ---------------- depthwise causal conv K=4 + silu ----------------
__global__ __launch_bounds__(256) void conv_silu_k(const u16* __restrict__ h, const void* __restrict__ cw,
                                                   const void* __restrict__ cb, u16* __restrict__ out,
                                                   const int* __restrict__ fl) {
    int f = *fl;
    int m = blockIdx.x, tid = threadIdx.x;
    int b = m >> 12, t = m & (TLEN - 1);
    int c = tid * 8;
    float acc[8];
#pragma unroll
    for (int i = 0; i < 8; ++i) acc[i] = ld1f(cb, c + i, f);
    float wv[8][4];
#pragma unroll
    for (int i = 0; i < 8; ++i) {
        if (f) {
            float4 wp = *(const float4*)((const float*)cw + (size_t)(c + i) * 4);
            wv[i][0] = wp.x; wv[i][1] = wp.y; wv[i][2] = wp.z; wv[i][3] = wp.w;
        } else {
            uint2 wp = *(const uint2*)((const u16*)cw + (size_t)(c + i) * 4);
            wv[i][0] = bf2f(wp.x & 0xffffu); wv[i][1] = bf2f(wp.x >> 16);
            wv[i][2] = bf2f(wp.y & 0xffffu); wv[i][3] = bf2f(wp.y >> 16);
        }
    }
#pragma unroll
    for (int j = 0; j < 4; ++j) {
        int tj = t - 3 + j;
        if (tj < 0) continue;
        uint4 hp = *(const uint4*)&h[((size_t)(b * TLEN + tj)) * D_MODEL + c];
        float hv[8];
        unpack8(hp, hv);
#pragma unroll
        for (int i = 0; i < 8; ++i) acc[i] += wv[i][j] * hv[i];
    }
    float o[8];
#pragma unroll
    for (int i = 0; i < 8; ++i) o[i] = acc[i] * sigmoidf_(acc[i]);
    *(uint4*)&out[(size_t)m * D_MODEL + c] = pack8(o);
}

// ---------------- bf16 GEMM: C[m,n] = sum_k A[m,k]*BT[n,k] ----------------
// 256x256 tile, BK=64, 512 thr (8 waves, 2Mx4N), 128 KiB LDS double-buffer,
// 8-phase schedule: per phase {ds_read subtile; stage 1 half-tile (2x
// global_load_lds); s_barrier; setprio(1); 16 MFMA; setprio(0); s_barrier}.
// Counted s_waitcnt vmcnt(4) at phases 4/8 only (loads stay in flight across
// barriers). LDS swizzle: row-major [256][64] u16 tiles, 16-B slot index s of
// row r holds global chunk s ^ (r&7). gload_lds dest stays LINEAR; the GLOBAL
// source chunk is pre-XORed; ds_read applies the same XOR (involution).
// Conflict-free: a b128 fragment read's aligned 8-lane group = 8 consecutive
// rows x fixed chunk -> slots 0..7 -> all 32 banks exactly once.
// Tail: stage addrs clamp to tile NT-1 with FIXED buffer targets so the
// vmcnt counting stays uniform (predicating stages would break it).
// EPI 0: bf16 store.
// EPI 1: bf16 = sigmoid(acc + rawbias[n])            (aux raw-flagged)
// EPI 2: bf16 = acc + raw_resid[m,n]                 (aux raw-flagged, e.g. x)
// EPI 3: bf16 = silu(bf16 aux[m,n]) * acc            (aux canonical; may alias out)
// EPI 4: out[oofs+m*N+n] = acc + bf16 aux[m,n]; out dtype per flag (f32/bf16)
template <int EPI>
__global__ __launch_bounds__(512, 2) void gemm256(const u16* __restrict__ A, const u16* __restrict__ BT,
                                                  void* out, const void* aux, const int* fl,
                                                  long long oofs, int M, int N, int K) {
    __shared__ u16 As[2][16384];   // [buf][256 rows][64 k]
    __shared__ u16 Bs[2][16384];
    const int tid = threadIdx.x;
    const int lane = tid & 63;
    const int wv = tid >> 6;       // wave 0..7
    const int wm = wv >> 2;        // 0..1  (M half: 128 rows)
    const int wn = wv & 3;         // 0..3  (N quarter: 64 cols)
    const int m0 = blockIdx.y * 256, n0 = blockIdx.x * 256;

    // staging: thread stages rows r0 (q=0) / r0+64 (q=1) of each 128-row half.
    // Global source chunk = (tid&7) ^ (row&7)  [full-row XOR swizzle, 16B units]
    const int r0 = tid >> 3;
    const int cS = (((tid & 7) ^ (r0 & 7)) << 3);
    const u16* aB = A + (size_t)(m0 + r0) * K + cS;
    const u16* bB = BT + (size_t)(n0 + r0) * K + cS;

    // read-side fragment offsets (ushort units): global chunk c of row r lives
    // at slot c ^ (r&7). fr = fragment row, c = lane>>4 (k-chunk within 32-k).
    const int fr = lane & 15;
    const int cc = lane >> 4;                 // 0..3
    const int rx = fr & 7;
    const int rdA0 = (wm * 128 + fr) * 64 + ((cc ^ rx) << 3);
    const int rdA1 = (wm * 128 + fr) * 64 + (((cc ^ 4) ^ rx) << 3);
    const int rdB0 = (wn * 64 + fr) * 64 + ((cc ^ rx) << 3);
    const int rdB1 = (wn * 64 + fr) * 64 + (((cc ^ 4) ^ rx) << 3);

    f32x4 acc[8][4];
#pragma unroll
    for (int i = 0; i < 8; ++i)
#pragma unroll
        for (int j = 0; j < 4; ++j) acc[i][j] = (f32x4)0.0f;

    bf16x8 a[4][2], b0[2][2], b1[2][2];

#define BARX() asm volatile("s_barrier" ::: "memory")
#define WAITV(n) asm volatile("s_waitcnt vmcnt(" #n ")" ::: "memory")
#define STG_A(sel, h, tI)                                                                        \
    do {                                                                                         \
        async16(aB + (size_t)((h) * 128) * K + (size_t)(tI) * 64,                                \
                &As[sel][(h) * 8192 + (tid >> 6) * 512]);                                        \
        async16(aB + (size_t)((h) * 128 + 64) * K + (size_t)(tI) * 64,                           \
                &As[sel][(h) * 8192 + 4096 + (tid >> 6) * 512]);                                 \
    } while (0)
#define STG_B(sel, h, tI)                                                                        \
    do {                                                                                         \
        async16(bB + (size_t)((h) * 128) * K + (size_t)(tI) * 64,                                \
                &Bs[sel][(h) * 8192 + (tid >> 6) * 512]);                                        \
        async16(bB + (size_t)((h) * 128 + 64) * K + (size_t)(tI) * 64,                           \
                &Bs[sel][(h) * 8192 + 4096 + (tid >> 6) * 512]);                                 \
    } while (0)
#define LDA4(s, base)                                                                            \
    do {                                                                                         \
        a[0][0] = *(const bf16x8*)&As[s][rdA0 + (base + 0) * 1024];                              \
        a[0][1] = *(const bf16x8*)&As[s][rdA1 + (base + 0) * 1024];                              \
        a[1][0] = *(const bf16x8*)&As[s][rdA0 + (base + 1) * 1024];                              \
        a[1][1] = *(const bf16x8*)&As[s][rdA1 + (base + 1) * 1024];                              \
        a[2][0] = *(const bf16x8*)&As[s][rdA0 + (base + 2) * 1024];                              \
        a[2][1] = *(const bf16x8*)&As[s][rdA1 + (base + 2) * 1024];                              \
        a[3][0] = *(const bf16x8*)&As[s][rdA0 + (base + 3) * 1024];                              \
        a[3][1] = *(const bf16x8*)&As[s][rdA1 + (base + 3) * 1024];                              \
    } while (0)
#define LDB2(s, base, bb)                                                                        \
    do {                                                                                         \
        bb[0][0] = *(const bf16x8*)&Bs[s][rdB0 + (base + 0) * 1024];                             \
        bb[0][1] = *(const bf16x8*)&Bs[s][rdB1 + (base + 0) * 1024];                             \
        bb[1][0] = *(const bf16x8*)&Bs[s][rdB0 + (base + 1) * 1024];                             \
        bb[1][1] = *(const bf16x8*)&Bs[s][rdB1 + (base + 1) * 1024];                             \
    } while (0)
#define MM8(I0, J0, bb)                                                                          \
    do {                                                                                         \
        __builtin_amdgcn_s_setprio(1);                                                           \
        _Pragma("unroll") for (int i_ = 0; i_ < 4; ++i_) {                                       \
            _Pragma("unroll") for (int j_ = 0; j_ < 2; ++j_) {                                   \
                acc[(I0) + i_][(J0) + j_] = __builtin_amdgcn_mfma_f32_16x16x32_bf16(             \
                    a[i_][0], bb[j_][0], acc[(I0) + i_][(J0) + j_], 0, 0, 0);                    \
                acc[(I0) + i_][(J0) + j_] = __builtin_amdgcn_mfma_f32_16x16x32_bf16(             \
                    a[i_][1], bb[j_][1], acc[(I0) + i_][(J0) + j_], 0, 0, 0);                    \
            }                                                                                    \
        }                                                                                        \
        __builtin_amdgcn_s_setprio(0);                                                           \
    } while (0)

    // prologue: tile0 full + B halves of tile1; force tile0 landed (4 newest ok)
    STG_A(0, 0, 0);
    STG_A(0, 1, 0);
    STG_B(0, 0, 0);
    STG_B(0, 1, 0);
    STG_B(1, 0, 1);
    STG_B(1, 1, 1);
    WAITV(4);
    BARX();

    const int NT = K >> 6;
    for (int t = 0; t < NT; t += 2) {
        const int tn = t + 1;
        const int t2 = (t + 2 < NT) ? t + 2 : NT - 1;
        const int t3 = (t + 3 < NT) ? t + 3 : NT - 1;
        // phase 1: tile t Q(M0-3,N0-1); stage A-h0(t+1)->buf1
        LDA4(0, 0);
        LDB2(0, 0, b0);
        STG_A(1, 0, tn);
        BARX();
        MM8(0, 0, b0);
        BARX();
        // phase 2: Q(M0-3,N2-3); stage A-h1(t+1)->buf1
        LDB2(0, 2, b1);
        STG_A(1, 1, tn);
        BARX();
        MM8(0, 2, b1);
        BARX();
        // phase 3: Q(M4-7,N0-1); stage B-h0(t+2)->buf0 (buf0.B reads done ph2)
        LDA4(0, 4);
        STG_B(0, 0, t2);
        BARX();
        MM8(4, 0, b0);
        BARX();
        // phase 4: Q(M4-7,N2-3); stage B-h1(t+2)->buf0; force tile t+1 landed
        STG_B(0, 1, t2);
        BARX();
        MM8(4, 2, b1);
        WAITV(4);
        BARX();
        // phase 5: tile t+1 Q(M0-3,N0-1); stage A-h0(t+2)->buf0 (buf0.A reads done ph3)
        LDA4(1, 0);
        LDB2(1, 0, b0);
        STG_A(0, 0, t2);
        BARX();
        MM8(0, 0, b0);
        BARX();
        // phase 6: Q(M0-3,N2-3); stage A-h1(t+2)->buf0
        LDB2(1, 2, b1);
        STG_A(0, 1, t2);
        BARX();
        MM8(0, 2, b1);
        BARX();
        // phase 7: Q(M4-7,N0-1); stage B-h0(t+3)->buf1 (buf1.B reads done ph6)
        LDA4(1, 4);
        STG_B(1, 0, t3);
        BARX();
        MM8(4, 0, b0);
        BARX();
        // phase 8: Q(M4-7,N2-3); stage B-h1(t+3)->buf1; force tile t+2 landed
        STG_B(1, 1, t3);
        BARX();
        MM8(4, 2, b1);
        WAITV(4);
        BARX();
    }
    WAITV(0);  // drain clamped tail stages before endpgm

#undef BARX
#undef WAITV
#undef STG_A
#undef STG_B
#undef LDA4
#undef LDB2
#undef MM8

    int f = (EPI == 1 || EPI == 2 || EPI == 4) ? *fl : 0;
    const int col0 = n0 + wn * 64 + (lane & 15);
    const int row0 = m0 + wm * 128 + ((lane >> 4) << 2);
#pragma unroll
    for (int i = 0; i < 8; ++i) {
#pragma unroll
        for (int r = 0; r < 4; ++r) {
            int row = row0 + i * 16 + r;
            size_t base = (size_t)row * N;
#pragma unroll
            for (int j = 0; j < 4; ++j) {
                int col = col0 + j * 16;
                float v = acc[i][j][r];
                if (EPI == 0) {
                    ((u16*)out)[base + col] = f2bf(v);
                } else if (EPI == 1) {
                    ((u16*)out)[base + col] = f2bf(sigmoidf_(v + ld1f(aux, col, f)));
                } else if (EPI == 2) {
                    ((u16*)out)[base + col] = f2bf(v + ld1f(aux, base + col, f));
                } else if (EPI == 3) {
                    float g = bf2f(((const u16*)aux)[base + col]);
                    ((u16*)out)[base + col] = f2bf(g * sigmoidf_(g) * v);
                } else {
                    float hr = bf2f(((const u16*)aux)[base + col]);
                    if (f) ((float*)out)[oofs + base + col] = v + hr;
                    else   ((u16*)out)[oofs + base + col] = f2bf(v + hr);
                }
            }
        }
    }
}

// ---------------- per-head l2norm (in place) ----------------
__global__ __launch_bounds__(256) void l2norm_k(u16* __restrict__ x) {
    int m = blockIdx.x, tid = threadIdx.x;
    size_t base = (size_t)m * D_MODEL + tid * 8;
    uint4 p = *(const uint4*)&x[base];
    float v[8];
    unpack8(p, v);
    float s = 0.f;
#pragma unroll
    for (int i = 0; i < 8; ++i) s += v[i] * v[i];
    s += __shfl_xor(s, 1, 64); s += __shfl_xor(s, 2, 64);
    s += __shfl_xor(s, 4, 64); s += __shfl_xor(s, 8, 64);
    float sc = rsqrtf(s + 1e-12f);
    float o[8];
#pragma unroll
    for (int i = 0; i < 8; ++i) o[i] = v[i] * sc;
    *(uint4*)&x[base] = pack8(o);
}

// ---------------- per-head LayerNorm (in place), D=128 ----------------
__global__ __launch_bounds__(256) void vnorm_k(u16* __restrict__ x, const void* __restrict__ w,
                                               const void* __restrict__ bb, const int* __restrict__ fl) {
    int f = *fl;
    int m = blockIdx.x, tid = threadIdx.x;
    size_t base = (size_t)m * D_MODEL + tid * 8;
    uint4 p = *(const uint4*)&x[base];
    float v[8];
    unpack8(p, v);
    float s = 0.f, ss = 0.f;
#pragma unroll
    for (int i = 0; i < 8; ++i) { s += v[i]; ss += v[i] * v[i]; }
    s += __shfl_xor(s, 1, 64); s += __shfl_xor(s, 2, 64);
    s += __shfl_xor(s, 4, 64); s += __shfl_xor(s, 8, 64);
    ss += __shfl_xor(ss, 1, 64); ss += __shfl_xor(ss, 2, 64);
    ss += __shfl_xor(ss, 4, 64); ss += __shfl_xor(ss, 8, 64);
    float mu = s * (1.f / HEADDIM);
    float var = ss * (1.f / HEADDIM) - mu * mu;
    float rs = rsqrtf(var + 1e-5f);
    int d0 = (tid * 8) & 127;
    float o[8];
#pragma unroll
    for (int i = 0; i < 8; ++i) o[i] = (v[i] - mu) * rs * ld1f(w, d0 + i, f) + ld1f(bb, d0 + i, f);
    *(uint4*)&x[base] = pack8(o);
}

// ---------------- gamma[m,h] = sigmoid(xc[m,:] @ Wg[:,h] + bg[h]) ----------------
__global__ __launch_bounds__(256) void gamma_k(const u16* __restrict__ xc, const void* __restrict__ Wg,
                                               const void* __restrict__ bg, float* __restrict__ gamma,
                                               const int* __restrict__ fl) {
    int f = *fl;
    int m = blockIdx.x, tid = threadIdx.x;
    float g[16];
#pragma unroll
    for (int h = 0; h < 16; ++h) g[h] = 0.f;
    size_t base = (size_t)m * D_MODEL + tid * 8;
    uint4 xp = *(const uint4*)&xc[base];
    float xv[8];
    unpack8(xp, xv);
#pragma unroll
    for (int i = 0; i < 8; ++i) {
        float wv[16];
        size_t ro = (size_t)(tid * 8 + i) * 16;
        if (f) {
            const float4* wr = (const float4*)((const float*)Wg + ro);
#pragma unroll
            for (int q = 0; q < 4; ++q) {
                float4 w4 = wr[q];
                wv[q * 4 + 0] = w4.x; wv[q * 4 + 1] = w4.y; wv[q * 4 + 2] = w4.z; wv[q * 4 + 3] = w4.w;
            }
        } else {
            const u16* wrow = (const u16*)Wg + ro;
            uint4 w0 = *(const uint4*)&wrow[0];
            uint4 w1 = *(const uint4*)&wrow[8];
            unpack8(w0, wv);
            unpack8(w1, wv + 8);
        }
#pragma unroll
        for (int h = 0; h < 16; ++h) g[h] += xv[i] * wv[h];
    }
#pragma unroll
    for (int h = 0; h < 16; ++h)
#pragma unroll
        for (int off = 32; off; off >>= 1) g[h] += __shfl_xor(g[h], off, 64);
    __shared__ float part[4][16];
    int lane = tid & 63, wvi = tid >> 6;
    if (lane == 0)
#pragma unroll
        for (int h = 0; h < 16; ++h) part[wvi][h] = g[h];
    __syncthreads();
    if (tid < 16) {
        float s = part[0][tid] + part[1][tid] + part[2][tid] + part[3][tid] + ld1f(bg, tid, f);
        gamma[(size_t)m * 16 + tid] = sigmoidf_(s);
    }
}

// ---------------- chunked gated scan, phase 1: local scans + prefix products ----------------
__global__ __launch_bounds__(256) void scan1(const u16* __restrict__ ig, const u16* __restrict__ kn,
                                             const u16* __restrict__ vn, const float* __restrict__ gamma,
                                             float* __restrict__ mem, float* __restrict__ pp) {
    int idx = blockIdx.x;              // B * NCHUNK * 8
    int cblk = idx & 7, ch = (idx >> 3) & (NCHUNK - 1), b = idx >> 8;
    int c = cblk * 256 + threadIdx.x;
    int h = c >> 7;
    float mval = 0.f, p = 1.f;
    int t0 = ch * CHUNK;
    size_t rowbase = ((size_t)(b * TLEN + t0)) * D_MODEL + c;
    size_t grow = (size_t)(b * TLEN + t0) * 16 + h;
    bool writepp = ((c & 127) == 0);
    for (int s = 0; s < CHUNK; ++s) {
        float u = bf2f(ig[rowbase]) * bf2f(kn[rowbase]) * bf2f(vn[rowbase]);
        float g = gamma[grow];
        mval = g * mval + u;
        p *= g;
        mem[rowbase] = mval;
        if (writepp) pp[grow] = p;
        rowbase += D_MODEL;
        grow += 16;
    }
}

// ---------------- phase 2: serial carry across chunks ----------------
__global__ __launch_bounds__(256) void scan2(const float* __restrict__ mem, const float* __restrict__ pp,
                                             float* __restrict__ carry) {
    int idx = blockIdx.x * 256 + threadIdx.x;  // B*C = 4096
    int b = idx >> 11, c = idx & 2047, h = c >> 7;
    float cy = 0.f;
    for (int ch = 0; ch < NCHUNK; ++ch) {
        carry[((size_t)(b * NCHUNK + ch)) * D_MODEL + c] = cy;
        int tend = ch * CHUNK + CHUNK - 1;
        float P = pp[((size_t)(b * TLEN + tend)) * 16 + h];
        float le = mem[((size_t)(b * TLEN + tend)) * D_MODEL + c];
        cy = P * cy + le;
    }
}

// ---------------- attn epilogue: carry-fix + LN(mem)*q -> GroupNorm -> *og ----------------
__global__ __launch_bounds__(256) void attn_epi(const float* __restrict__ mem, const float* __restrict__ pp,
                                                const float* __restrict__ carry, const u16* __restrict__ qn,
                                                const u16* __restrict__ og, const void* __restrict__ mnw,
                                                const void* __restrict__ mnb, const void* __restrict__ gnw,
                                                const void* __restrict__ gnb, u16* __restrict__ outb,
                                                const int* __restrict__ fl) {
    int f = *fl;
    int m = blockIdx.x, tid = threadIdx.x;
    int b = m >> 12, t = m & (TLEN - 1);
    int ch = t >> 7;
    int c = tid * 8, h = c >> 7;
    size_t base = (size_t)m * D_MODEL + c;
    float mv[8];
    {
        const float4* p = (const float4*)&mem[base];
        float4 a = p[0], bb4 = p[1];
        mv[0] = a.x; mv[1] = a.y; mv[2] = a.z; mv[3] = a.w;
        mv[4] = bb4.x; mv[5] = bb4.y; mv[6] = bb4.z; mv[7] = bb4.w;
    }
    float ppv = pp[(size_t)m * 16 + h];
    {
        const float4* p = (const float4*)&carry[((size_t)(b * NCHUNK + ch)) * D_MODEL + c];
        float4 a = p[0], bb4 = p[1];
        mv[0] += ppv * a.x; mv[1] += ppv * a.y; mv[2] += ppv * a.z; mv[3] += ppv * a.w;
        mv[4] += ppv * bb4.x; mv[5] += ppv * bb4.y; mv[6] += ppv * bb4.z; mv[7] += ppv * bb4.w;
    }
    float s = 0.f, ss = 0.f;
#pragma unroll
    for (int i = 0; i < 8; ++i) { s += mv[i]; ss += mv[i] * mv[i]; }
    s += __shfl_xor(s, 1, 64); s += __shfl_xor(s, 2, 64);
    s += __shfl_xor(s, 4, 64); s += __shfl_xor(s, 8, 64);
    ss += __shfl_xor(ss, 1, 64); ss += __shfl_xor(ss, 2, 64);
    ss += __shfl_xor(ss, 4, 64); ss += __shfl_xor(ss, 8, 64);
    float mu = s * (1.f / HEADDIM);
    float var = ss * (1.f / HEADDIM) - mu * mu;
    float rs = rsqrtf(var + 1e-5f);
    int d0 = c & 127;
    uint4 qp = *(const uint4*)&qn[base];
    float qv[8];
    unpack8(qp, qv);
    float o[8];
#pragma unroll
    for (int i = 0; i < 8; ++i)
        o[i] = ((mv[i] - mu) * rs * ld1f(mnw, d0 + i, f) + ld1f(mnb, d0 + i, f)) * qv[i];
    float s2 = 0.f, ss2 = 0.f;
#pragma unroll
    for (int i = 0; i < 8; ++i) { s2 += o[i]; ss2 += o[i] * o[i]; }
    s2 += __shfl_xor(s2, 1, 64); s2 += __shfl_xor(s2, 2, 64);
    s2 += __shfl_xor(s2, 4, 64); s2 += __shfl_xor(s2, 8, 64);
    ss2 += __shfl_xor(ss2, 1, 64); ss2 += __shfl_xor(ss2, 2, 64);
    ss2 += __shfl_xor(ss2, 4, 64); ss2 += __shfl_xor(ss2, 8, 64);
    float mu2 = s2 * (1.f / HEADDIM);
    float var2 = ss2 * (1.f / HEADDIM) - mu2 * mu2;
    float rs2 = rsqrtf(var2 + 1e-5f);
    uint4 ogp = *(const uint4*)&og[base];
    float ogv[8];
    unpack8(ogp, ogv);
    float ob[8];
#pragma unroll
    for (int i = 0; i < 8; ++i)
        ob[i] = ((o[i] - mu2) * rs2 * ld1f(gnw, c + i, f) + ld1f(gnb, c + i, f)) * ogv[i];
    *(uint4*)&outb[base] = pack8(ob);
}

// ---------------- workspace arena: 8 slots x 32 MiB = 256 MiB peak ----------------
// slot0: wT (8 MiB, reused) + gamma/pp/carry/flagA @16MiB -> wTgate (32 MiB, MLP)
// slot1: hb      -> mem[lo]  -> wTval
// slot2: xcb     -> mem[hi]  -> wTout
// slot3: qn      -> h2b
// slot4: kn      -> attn     -> flagB (MLP phase)
// slot5: vn      -> hres (bf16)
// slot6: ig      -> graw[lo]
// slot7: og      -> graw[hi]
#define SLOT 33554432ull
#define WS_NEED (SLOT * 8)
#define FLAGA_OFF 18350080ull   /* slot0 + 16MiB + 1.5MiB (after carry) */
#define FLAGB_OFF (SLOT * 4)

extern "C" void kernel_launch(void* const* d_in, const int* in_sizes, int n_in,
                              void* d_out, int out_size, void* d_ws, size_t ws_size,
                              hipStream_t stream) {
    if (ws_size < WS_NEED) return;  // diagnostic guard: fail absmax instead of crashing

    const void* x     = d_in[0];
    const void* Wq    = d_in[1];
    const void* Wk    = d_in[2];
    const void* Wv    = d_in[3];
    const void* Wo    = d_in[4];
    const void* convw = d_in[5];
    const void* convb = d_in[6];
    const void* Wig   = d_in[7];
    const void* big   = d_in[8];
    const void* Wog   = d_in[9];
    const void* bog   = d_in[10];
    const void* Wg    = d_in[11];
    const void* bg    = d_in[12];
    const void* vnw   = d_in[13];
    const void* vnb   = d_in[14];
    const void* mnw   = d_in[15];
    const void* mnb   = d_in[16];
    const void* gnw   = d_in[17];
    const void* gnb   = d_in[18];
    const void* ln1w  = d_in[19];
    const void* ln1b  = d_in[20];
    const void* ln2w  = d_in[21];
    const void* ln2b  = d_in[22];
    const void* Wgate = d_in[23];
    const void* Wval  = d_in[24];
    const void* Wout  = d_in[25];

    char* ws = (char*)d_ws;
    u16* wT      = (u16*)(ws);
    float* gamma = (float*)(ws + 16777216);
    float* pp    = (float*)(ws + 16777216 + 524288);
    float* carry = (float*)(ws + 16777216 + 1048576);
    int* flagA   = (int*)(ws + FLAGA_OFF);
    int* flagB   = (int*)(ws + FLAGB_OFF);
    u16* hb      = (u16*)(ws + SLOT * 1);
    u16* xcb     = (u16*)(ws + SLOT * 2);
    float* mem   = (float*)(ws + SLOT * 1);          // spans slots 1-2 (f32)
    u16* wTgate  = (u16*)(ws);                       // slot0 (32 MiB), MLP phase
    u16* wTval   = (u16*)(ws + SLOT * 1);
    u16* wTout   = (u16*)(ws + SLOT * 2);
    u16* qn      = (u16*)(ws + SLOT * 3);
    u16* h2b     = (u16*)(ws + SLOT * 3);
    u16* kn      = (u16*)(ws + SLOT * 4);
    u16* attn    = (u16*)(ws + SLOT * 4);
    u16* vn      = (u16*)(ws + SLOT * 5);
    u16* hres    = (u16*)(ws + SLOT * 5);
    u16* ig      = (u16*)(ws + SLOT * 6);
    u16* og      = (u16*)(ws + SLOT * 7);
    u16* graw    = (u16*)(ws + SLOT * 6);            // spans slots 6-7

    dim3 tb(32, 8);

    detect_k<<<1, 256, 0, stream>>>((const u16*)x, flagA);

    // ---- attention front-end ----
    ln_rows<1><<<MTOK, 256, 0, stream>>>(x, hb, ln1w, ln1b, flagA);
    conv_silu_k<<<MTOK, 256, 0, stream>>>(hb, convw, convb, xcb, flagA);

    transpose_k<<<dim3(64, 64), tb, 0, stream>>>(Wq, wT, 2048, 2048, flagA);
    gemm256<0><<<dim3(8, 32), 512, 0, stream>>>(hb, wT, qn, nullptr, nullptr, 0, MTOK, 2048, 2048);
    transpose_k<<<dim3(64, 64), tb, 0, stream>>>(Wk, wT, 2048, 2048, flagA);
    gemm256<0><<<dim3(8, 32), 512, 0, stream>>>(hb, wT, kn, nullptr, nullptr, 0, MTOK, 2048, 2048);
    transpose_k<<<dim3(64, 64), tb, 0, stream>>>(Wv, wT, 2048, 2048, flagA);
    gemm256<0><<<dim3(8, 32), 512, 0, stream>>>(hb, wT, vn, nullptr, nullptr, 0, MTOK, 2048, 2048);
    l2norm_k<<<MTOK, 256, 0, stream>>>(qn);
    l2norm_k<<<MTOK, 256, 0, stream>>>(kn);
    vnorm_k<<<MTOK, 256, 0, stream>>>(vn, vnw, vnb, flagA);

    transpose_k<<<dim3(64, 64), tb, 0, stream>>>(Wig, wT, 2048, 2048, flagA);
    gemm256<1><<<dim3(8, 32), 512, 0, stream>>>(xcb, wT, ig, big, flagA, 0, MTOK, 2048, 2048);
    transpose_k<<<dim3(64, 64), tb, 0, stream>>>(Wog, wT, 2048, 2048, flagA);
    gemm256<1><<<dim3(8, 32), 512, 0, stream>>>(xcb, wT, og, bog, flagA, 0, MTOK, 2048, 2048);
    gamma_k<<<MTOK, 256, 0, stream>>>(xcb, Wg, bg, gamma, flagA);

    // ---- gated scan (mem overwrites hb/xcb slots — both dead) ----
    scan1<<<BSZ * NCHUNK * 8, 256, 0, stream>>>(ig, kn, vn, gamma, mem, pp);
    scan2<<<16, 256, 0, stream>>>(mem, pp, carry);
    attn_epi<<<MTOK, 256, 0, stream>>>(mem, pp, carry, qn, og, mnw, mnb, gnw, gnb, attn, flagA);

    // ---- output projection + residual (hres bf16) ----
    transpose_k<<<dim3(64, 64), tb, 0, stream>>>(Wo, wT, 2048, 2048, flagA);
    gemm256<2><<<dim3(8, 32), 512, 0, stream>>>(attn, wT, hres, x, flagA, 0, MTOK, 2048, 2048);
    ln_rows<0><<<MTOK, 256, 0, stream>>>(hres, h2b, ln2w, ln2b, flagA);

    // ---- flag to MLP-phase home (slot4 free after Wo gemm) ----
    copyflag_k<<<1, 1, 0, stream>>>(flagA, flagB);

    // ---- MLP: transpose all three weights once, then two M=4096 halves ----
    transpose_k<<<dim3(256, 64), tb, 0, stream>>>(Wgate, wTgate, 2048, 8192, flagB);
    transpose_k<<<dim3(256, 64), tb, 0, stream>>>(Wval, wTval, 2048, 8192, flagB);
    transpose_k<<<dim3(64, 256), tb, 0, stream>>>(Wout, wTout, 8192, 2048, flagB);

    for (int half = 0; half < 2; ++half) {
        const u16* a2 = h2b + (size_t)half * 4096 * 2048;
        const u16* hr = hres + (size_t)half * 4096 * 2048;
        long long oofs = (long long)half * 4096 * 2048;
        gemm256<0><<<dim3(32, 16), 512, 0, stream>>>(a2, wTgate, graw, nullptr, nullptr, 0, 4096, 8192, 2048);
        gemm256<3><<<dim3(32, 16), 512, 0, stream>>>(a2, wTval, graw, graw, nullptr, 0, 4096, 8192, 2048);
        gemm256<4><<<dim3(8, 16), 512, 0, stream>>>(graw, wTout, d_out, hr, flagB, oofs, 4096, 2048, 8192);
    }
}